// Round 1
// baseline (312.646 us; speedup 1.0000x reference)
//
#include <hip/hip_runtime.h>
#include <cstdint>
#include <cstddef>

// Problem constants (from reference setup_inputs)
#define NB 8
#define CH 256
#define DD 8
#define HH 16
#define WW 16
#define PP 2048          // D*H*W
#define MAXL 32          // max positives per q-voxel (geometric bound ~9; 32 is very safe)

// Workspace layout (bytes):
//   [0,            65536)              int    counts[NB*PP]
//   [65536,        65536+1048576)      ushort lists[NB*MAXL*PP]   (layout [n][j][p] for coalesced reads)
//   [1114112,      1114144)            float  num[NB]
//   [1114144,      1114176)            int    cntn[NB]
#define OFF_LIST  65536
#define OFF_NUM   1114112
#define OFF_CNTN  1114144

__global__ __launch_bounds__(64) void zero_kernel(float* __restrict__ num,
                                                  int* __restrict__ cntn) {
    int t = threadIdx.x;
    if (t < NB) { num[t] = 0.0f; cntn[t] = 0; }
}

// Kernel A: one wave per (n,p). Scan all 2048 k-voxels, compact positive
// indices into lists[n][j][p] via ballot prefix. Mask math mirrors the numpy
// fp32 reference op-for-op (__f*_rn prevents FMA contraction).
__global__ __launch_bounds__(256) void mask_kernel(
    const float* __restrict__ coord_q, const float* __restrict__ coord_k,
    int* __restrict__ counts, unsigned short* __restrict__ lists,
    int* __restrict__ cntn)
{
    int wave = blockIdx.x * 4 + (threadIdx.x >> 6);
    int lane = threadIdx.x & 63;
    int n = wave >> 11;          // wave / 2048
    int p = wave & (PP - 1);

    const float* cq = coord_q + n * 6;
    const float* ck = coord_k + n * 6;
    float q0 = cq[0], q1 = cq[1], q2 = cq[2];
    float bwq = __fdiv_rn(__fsub_rn(cq[3], q0), (float)WW);
    float bhq = __fdiv_rn(__fsub_rn(cq[4], q1), (float)HH);
    float bdq = __fdiv_rn(__fsub_rn(cq[5], q2), (float)DD);
    float k0 = ck[0], k1 = ck[1], k2 = ck[2];
    float bwk = __fdiv_rn(__fsub_rn(ck[3], k0), (float)WW);
    float bhk = __fdiv_rn(__fsub_rn(ck[4], k1), (float)HH);
    float bdk = __fdiv_rn(__fsub_rn(ck[5], k2), (float)DD);

    float diagq = __fsqrt_rn(__fadd_rn(__fadd_rn(__fmul_rn(bwq, bwq), __fmul_rn(bhq, bhq)),
                                       __fmul_rn(bdq, bdq)));
    float diagk = __fsqrt_rn(__fadd_rn(__fadd_rn(__fmul_rn(bwk, bwk), __fmul_rn(bhk, bhk)),
                                       __fmul_rn(bdk, bdk)));
    float maxd = fmaxf(diagq, diagk);

    int ix = p & 15, iy = (p >> 4) & 15, iz = p >> 8;
    float cqx = __fadd_rn(__fmul_rn(__fadd_rn((float)ix, 0.5f), bwq), q0);
    float cqy = __fadd_rn(__fmul_rn(__fadd_rn((float)iy, 0.5f), bhq), q1);
    float cqz = __fadd_rn(__fmul_rn(__fadd_rn((float)iz, 0.5f), bdq), q2);

    float half_maxd = 0.5f * maxd;
    float thr2 = half_maxd * half_maxd * 1.001f;   // conservative prefilter (exact check inside)

    int count = 0;
    for (int it = 0; it < PP / 64; ++it) {
        int pp = (it << 6) | lane;
        int jx = pp & 15, jy = (pp >> 4) & 15, jz = pp >> 8;
        float ckx = __fadd_rn(__fmul_rn(__fadd_rn((float)jx, 0.5f), bwk), k0);
        float cky = __fadd_rn(__fmul_rn(__fadd_rn((float)jy, 0.5f), bhk), k1);
        float ckz = __fadd_rn(__fmul_rn(__fadd_rn((float)jz, 0.5f), bdk), k2);
        float dx = __fsub_rn(cqx, ckx);
        float dy = __fsub_rn(cqy, cky);
        float dz = __fsub_rn(cqz, ckz);
        float d2 = __fadd_rn(__fadd_rn(__fmul_rn(dx, dx), __fmul_rn(dy, dy)),
                             __fmul_rn(dz, dz));
        bool pos = false;
        if (d2 < thr2) {   // cheap reject; exact fp32-mirrored check below
            float dist = __fdiv_rn(__fsqrt_rn(d2), maxd);
            pos = dist < 0.5f;
        }
        unsigned long long m = __ballot(pos);
        if (pos) {
            int pref = __popcll(m & ((1ull << lane) - 1ull));
            int j = count + pref;
            if (j < MAXL)
                lists[((size_t)(n * MAXL + j)) * PP + p] = (unsigned short)pp;
        }
        count += (int)__popcll(m);
    }
    if (lane == 0) {
        counts[n * PP + p] = count < MAXL ? count : MAXL;
        atomicAdd(&cntn[n], count);
    }
}

// Kernel B: block = 256 threads handling (n, p-tile=256, c-chunk=32).
// Coalesced q loads; per-thread gather-accumulate of its positive k's
// (gather addresses of adjacent lanes are mostly adjacent -> good coalescing).
#define PTILE 256
#define CCHUNK 32
__global__ __launch_bounds__(256) void dot_kernel(
    const float* __restrict__ q, const float* __restrict__ k,
    const int* __restrict__ counts, const unsigned short* __restrict__ lists,
    float* __restrict__ num)
{
    __shared__ unsigned short lidx[MAXL][PTILE];
    __shared__ short lcnt[PTILE];
    __shared__ float red[256];

    int t = threadIdx.x;
    int n = blockIdx.z;
    int p0 = blockIdx.x * PTILE;
    int c0 = blockIdx.y * CCHUNK;

    lcnt[t] = (short)counts[n * PP + p0 + t];
    for (int j = 0; j < MAXL; ++j)
        lidx[j][t] = lists[((size_t)(n * MAXL + j)) * PP + p0 + t];
    __syncthreads();

    int cnt = lcnt[t];
    float acc = 0.0f;
    size_t base = ((size_t)n * CH + c0) * PP;
    for (int c = 0; c < CCHUNK; ++c) {
        const float* qrow = q + base + (size_t)c * PP;
        const float* krow = k + base + (size_t)c * PP;
        float qv = qrow[p0 + t];
        float s = 0.0f;
        for (int j = 0; j < cnt; ++j)
            s += krow[lidx[j][t]];
        acc += qv * s;
    }

    red[t] = acc;
    __syncthreads();
    for (int off = 128; off > 0; off >>= 1) {
        if (t < off) red[t] += red[t + off];
        __syncthreads();
    }
    if (t == 0) atomicAdd(&num[n], red[0]);
}

__global__ __launch_bounds__(64) void final_kernel(const float* __restrict__ num,
                                                  const int* __restrict__ cntn,
                                                  float* __restrict__ out)
{
    if (threadIdx.x == 0) {
        float s = 0.0f;
        for (int n = 0; n < NB; ++n)
            s += num[n] / ((float)cntn[n] + 1e-6f);
        out[0] = -2.0f * (s / 8.0f);
    }
}

extern "C" void kernel_launch(void* const* d_in, const int* in_sizes, int n_in,
                              void* d_out, int out_size, void* d_ws, size_t ws_size,
                              hipStream_t stream) {
    const float* q       = (const float*)d_in[0];
    const float* k       = (const float*)d_in[1];
    const float* coord_q = (const float*)d_in[2];
    const float* coord_k = (const float*)d_in[3];
    float* out = (float*)d_out;

    char* w = (char*)d_ws;
    int* counts           = (int*)w;
    unsigned short* lists = (unsigned short*)(w + OFF_LIST);
    float* num            = (float*)(w + OFF_NUM);
    int* cntn             = (int*)(w + OFF_CNTN);

    zero_kernel<<<1, 64, 0, stream>>>(num, cntn);
    mask_kernel<<<(NB * PP) / 4, 256, 0, stream>>>(coord_q, coord_k, counts, lists, cntn);
    dot_kernel<<<dim3(PP / PTILE, CH / CCHUNK, NB), 256, 0, stream>>>(q, k, counts, lists, num);
    final_kernel<<<1, 64, 0, stream>>>(num, cntn, out);
}

// Round 2
// 107.254 us; speedup vs baseline: 2.9150x; 2.9150x over previous
//
#include <hip/hip_runtime.h>
#include <cstdint>
#include <cstddef>

// Problem constants (from reference setup_inputs)
#define NB 8
#define CH 256
#define DD 8
#define HH 16
#define WW 16
#define PP 2048          // D*H*W
#define MAXL 32          // max positives per q-voxel (geometric bound <=18; 32 is safe)

// Workspace layout (bytes):
//   [0,            65536)              int    counts[NB*PP]     (TRUE counts, unclamped)
//   [65536,        65536+1048576)      ushort lists[NB*MAXL*PP] (layout [n][j][p], coalesced in p)
//   [1114112,      1114144)            float  num[NB]
#define OFF_LIST  65536
#define OFF_NUM   1114112

__global__ __launch_bounds__(64) void zero_kernel(float* __restrict__ num) {
    int t = threadIdx.x;
    if (t < NB) num[t] = 0.0f;
}

// Kernel A: one wave per (n,p). Scan all 2048 k-voxels, compact positive
// indices into lists[n][j][p] via ballot prefix. Mask math mirrors the numpy
// fp32 reference op-for-op (__f*_rn prevents FMA contraction).
// NO global atomics (R1 lesson: 16K same-line cross-XCD atomics cost 191us).
__global__ __launch_bounds__(256) void mask_kernel(
    const float* __restrict__ coord_q, const float* __restrict__ coord_k,
    int* __restrict__ counts, unsigned short* __restrict__ lists)
{
    int wave = blockIdx.x * 4 + (threadIdx.x >> 6);
    int lane = threadIdx.x & 63;
    int n = wave >> 11;          // wave / 2048
    int p = wave & (PP - 1);

    const float* cq = coord_q + n * 6;
    const float* ck = coord_k + n * 6;
    float q0 = cq[0], q1 = cq[1], q2 = cq[2];
    float bwq = __fdiv_rn(__fsub_rn(cq[3], q0), (float)WW);
    float bhq = __fdiv_rn(__fsub_rn(cq[4], q1), (float)HH);
    float bdq = __fdiv_rn(__fsub_rn(cq[5], q2), (float)DD);
    float k0 = ck[0], k1 = ck[1], k2 = ck[2];
    float bwk = __fdiv_rn(__fsub_rn(ck[3], k0), (float)WW);
    float bhk = __fdiv_rn(__fsub_rn(ck[4], k1), (float)HH);
    float bdk = __fdiv_rn(__fsub_rn(ck[5], k2), (float)DD);

    float diagq = __fsqrt_rn(__fadd_rn(__fadd_rn(__fmul_rn(bwq, bwq), __fmul_rn(bhq, bhq)),
                                       __fmul_rn(bdq, bdq)));
    float diagk = __fsqrt_rn(__fadd_rn(__fadd_rn(__fmul_rn(bwk, bwk), __fmul_rn(bhk, bhk)),
                                       __fmul_rn(bdk, bdk)));
    float maxd = fmaxf(diagq, diagk);

    int ix = p & 15, iy = (p >> 4) & 15, iz = p >> 8;
    float cqx = __fadd_rn(__fmul_rn(__fadd_rn((float)ix, 0.5f), bwq), q0);
    float cqy = __fadd_rn(__fmul_rn(__fadd_rn((float)iy, 0.5f), bhq), q1);
    float cqz = __fadd_rn(__fmul_rn(__fadd_rn((float)iz, 0.5f), bdq), q2);

    float half_maxd = 0.5f * maxd;
    float thr2 = half_maxd * half_maxd * 1.001f;   // conservative prefilter (exact check inside)

    int count = 0;
    for (int it = 0; it < PP / 64; ++it) {
        int pp = (it << 6) | lane;
        int jx = pp & 15, jy = (pp >> 4) & 15, jz = pp >> 8;
        float ckx = __fadd_rn(__fmul_rn(__fadd_rn((float)jx, 0.5f), bwk), k0);
        float cky = __fadd_rn(__fmul_rn(__fadd_rn((float)jy, 0.5f), bhk), k1);
        float ckz = __fadd_rn(__fmul_rn(__fadd_rn((float)jz, 0.5f), bdk), k2);
        float dx = __fsub_rn(cqx, ckx);
        float dy = __fsub_rn(cqy, cky);
        float dz = __fsub_rn(cqz, ckz);
        float d2 = __fadd_rn(__fadd_rn(__fmul_rn(dx, dx), __fmul_rn(dy, dy)),
                             __fmul_rn(dz, dz));
        bool pos = false;
        if (d2 < thr2) {   // cheap reject; exact fp32-mirrored check below
            float dist = __fdiv_rn(__fsqrt_rn(d2), maxd);
            pos = dist < 0.5f;
        }
        unsigned long long m = __ballot(pos);
        if (pos) {
            int pref = __popcll(m & ((1ull << lane) - 1ull));
            int j = count + pref;
            if (j < MAXL)
                lists[((size_t)(n * MAXL + j)) * PP + p] = (unsigned short)pp;
        }
        count += (int)__popcll(m);
    }
    if (lane == 0)
        counts[n * PP + p] = count;   // true count (denominator); clamped at use
}

// Kernel B: block = 256 threads handling (n, p-tile=256, c-chunk=16).
// Coalesced q loads; 4-way channel unroll shares one LDS index read and gives
// 4 independent gather chains per j iteration.
#define PTILE 256
#define CCHUNK 16
__global__ __launch_bounds__(256) void dot_kernel(
    const float* __restrict__ q, const float* __restrict__ k,
    const int* __restrict__ counts, const unsigned short* __restrict__ lists,
    float* __restrict__ num)
{
    __shared__ unsigned short lidx[MAXL][PTILE];
    __shared__ float red[256];

    int t = threadIdx.x;
    int n = blockIdx.z;
    int p0 = blockIdx.x * PTILE;
    int c0 = blockIdx.y * CCHUNK;

    // Each thread loads (and later reads) only its own LDS column -> no sync.
    for (int j = 0; j < MAXL; ++j)
        lidx[j][t] = lists[((size_t)(n * MAXL + j)) * PP + p0 + t];
    int cnt = counts[n * PP + p0 + t];
    cnt = cnt < MAXL ? cnt : MAXL;

    float acc = 0.0f;
    size_t base = ((size_t)n * CH + c0) * PP;
    const float* qb = q + base + p0 + t;
    const float* kb = k + base;
    for (int c = 0; c < CCHUNK; c += 4) {
        float q0v = qb[(size_t)(c + 0) * PP];
        float q1v = qb[(size_t)(c + 1) * PP];
        float q2v = qb[(size_t)(c + 2) * PP];
        float q3v = qb[(size_t)(c + 3) * PP];
        const float* k0r = kb + (size_t)(c + 0) * PP;
        const float* k1r = kb + (size_t)(c + 1) * PP;
        const float* k2r = kb + (size_t)(c + 2) * PP;
        const float* k3r = kb + (size_t)(c + 3) * PP;
        float s0 = 0.0f, s1 = 0.0f, s2 = 0.0f, s3 = 0.0f;
        for (int j = 0; j < cnt; ++j) {
            int idx = lidx[j][t];
            s0 += k0r[idx];
            s1 += k1r[idx];
            s2 += k2r[idx];
            s3 += k3r[idx];
        }
        acc += q0v * s0 + q1v * s1 + q2v * s2 + q3v * s3;
    }

    red[t] = acc;
    __syncthreads();
    for (int off = 128; off > 0; off >>= 1) {
        if (t < off) red[t] += red[t + off];
        __syncthreads();
    }
    if (t == 0) atomicAdd(&num[n], red[0]);   // 1024 atomics total, spread over 8 addrs
}

// Final: one wave per batch sums true counts (denominator), thread 0 combines.
__global__ __launch_bounds__(512) void final_kernel(const float* __restrict__ num,
                                                    const int* __restrict__ counts,
                                                    float* __restrict__ out)
{
    __shared__ float denom[NB];
    int t = threadIdx.x;
    int n = t >> 6, lane = t & 63;
    int s = 0;
    for (int i = 0; i < PP / 64; ++i)
        s += counts[n * PP + i * 64 + lane];
    for (int off = 32; off > 0; off >>= 1)
        s += __shfl_down(s, off, 64);
    if (lane == 0) denom[n] = (float)s;
    __syncthreads();
    if (t == 0) {
        float r = 0.0f;
        for (int i = 0; i < NB; ++i)
            r += num[i] / (denom[i] + 1e-6f);
        out[0] = -2.0f * (r / (float)NB);
    }
}

extern "C" void kernel_launch(void* const* d_in, const int* in_sizes, int n_in,
                              void* d_out, int out_size, void* d_ws, size_t ws_size,
                              hipStream_t stream) {
    const float* q       = (const float*)d_in[0];
    const float* k       = (const float*)d_in[1];
    const float* coord_q = (const float*)d_in[2];
    const float* coord_k = (const float*)d_in[3];
    float* out = (float*)d_out;

    char* w = (char*)d_ws;
    int* counts           = (int*)w;
    unsigned short* lists = (unsigned short*)(w + OFF_LIST);
    float* num            = (float*)(w + OFF_NUM);

    zero_kernel<<<1, 64, 0, stream>>>(num);
    mask_kernel<<<(NB * PP) / 4, 256, 0, stream>>>(coord_q, coord_k, counts, lists);
    dot_kernel<<<dim3(PP / PTILE, CH / CCHUNK, NB), 256, 0, stream>>>(q, k, counts, lists, num);
    final_kernel<<<1, 512, 0, stream>>>(num, counts, out);
}

// Round 3
// 88.185 us; speedup vs baseline: 3.5454x; 1.2162x over previous
//
#include <hip/hip_runtime.h>
#include <cstdint>
#include <cstddef>

// Problem constants (from reference setup_inputs)
#define NB 8
#define CH 256
#define DD 8
#define HH 16
#define WW 16
#define PP 2048          // D*H*W ; one z-slab = HH*WW = 256 voxels
#define MAXL 32          // max positives per q-voxel (geometric bound <=18)

// Workspace layout (bytes):
//   [0,       65536)    int    counts[NB*PP]      (TRUE counts)
//   [65536, 1114112)    ushort lists[NB*MAXL*PP]  (layout [n][j][p], coalesced in p)
//   [1114112,1122304)   float  partial[NB*8*32]   (per dot-block partial numerators)
#define OFF_LIST  65536
#define OFF_PART  1114112

// Geometric z-window: any positive pair (fp32-exact per the numpy reference)
// satisfies |czq - czk| < 0.5*maxd (monotonicity: d2 >= dz^2, sqrt/div RN
// monotone). With margin 1.2e-4 the window spans AT MOST 2 k z-slabs
// (width 2*0.0383 << 2*bd=0.125). Returns first feasible zk (clamped to
// [0,DD-2]) or -1 if none.
__device__ __forceinline__ int z_window(float czq, float bdk, float k2, float maxd) {
    float lim = 0.500060f * maxd;
    int zk0 = -1;
    #pragma unroll
    for (int zk = 0; zk < DD; ++zk) {
        float czk = __fadd_rn(__fmul_rn(__fadd_rn((float)zk, 0.5f), bdk), k2);
        bool feas = fabsf(__fsub_rn(czq, czk)) < lim;
        if (feas && zk0 < 0) zk0 = zk;
    }
    if (zk0 > DD - 2) zk0 = DD - 2;
    return zk0;
}

// Kernel A: one wave per (n,p). Scan ONLY the 2 feasible k z-slabs (512
// candidates, 8 iters). Compact positive indices into lists[n][j][p] via
// ballot prefix. Pair math mirrors the numpy fp32 reference op-for-op.
__global__ __launch_bounds__(256) void mask_kernel(
    const float* __restrict__ coord_q, const float* __restrict__ coord_k,
    int* __restrict__ counts, unsigned short* __restrict__ lists)
{
    int wave = blockIdx.x * 4 + (threadIdx.x >> 6);
    int lane = threadIdx.x & 63;
    int n = wave >> 11;
    int p = wave & (PP - 1);

    const float* cq = coord_q + n * 6;
    const float* ck = coord_k + n * 6;
    float q0 = cq[0], q1 = cq[1], q2 = cq[2];
    float bwq = __fdiv_rn(__fsub_rn(cq[3], q0), (float)WW);
    float bhq = __fdiv_rn(__fsub_rn(cq[4], q1), (float)HH);
    float bdq = __fdiv_rn(__fsub_rn(cq[5], q2), (float)DD);
    float k0 = ck[0], k1 = ck[1], k2 = ck[2];
    float bwk = __fdiv_rn(__fsub_rn(ck[3], k0), (float)WW);
    float bhk = __fdiv_rn(__fsub_rn(ck[4], k1), (float)HH);
    float bdk = __fdiv_rn(__fsub_rn(ck[5], k2), (float)DD);

    float diagq = __fsqrt_rn(__fadd_rn(__fadd_rn(__fmul_rn(bwq, bwq), __fmul_rn(bhq, bhq)),
                                       __fmul_rn(bdq, bdq)));
    float diagk = __fsqrt_rn(__fadd_rn(__fadd_rn(__fmul_rn(bwk, bwk), __fmul_rn(bhk, bhk)),
                                       __fmul_rn(bdk, bdk)));
    float maxd = fmaxf(diagq, diagk);

    int ix = p & 15, iy = (p >> 4) & 15, iz = p >> 8;
    float cqx = __fadd_rn(__fmul_rn(__fadd_rn((float)ix, 0.5f), bwq), q0);
    float cqy = __fadd_rn(__fmul_rn(__fadd_rn((float)iy, 0.5f), bhq), q1);
    float cqz = __fadd_rn(__fmul_rn(__fadd_rn((float)iz, 0.5f), bdq), q2);

    int zk0 = z_window(cqz, bdk, k2, maxd);
    if (zk0 < 0) {
        if (lane == 0) counts[n * PP + p] = 0;
        return;
    }
    int base_p = zk0 << 8;

    float half_maxd = 0.5f * maxd;
    float thr2 = half_maxd * half_maxd * 1.001f;   // conservative prefilter

    int count = 0;
    for (int it = 0; it < 8; ++it) {                 // 2 slabs = 512 candidates
        int pp = base_p + ((it << 6) | lane);
        int jx = pp & 15, jy = (pp >> 4) & 15, jz = pp >> 8;
        float ckx = __fadd_rn(__fmul_rn(__fadd_rn((float)jx, 0.5f), bwk), k0);
        float cky = __fadd_rn(__fmul_rn(__fadd_rn((float)jy, 0.5f), bhk), k1);
        float ckz = __fadd_rn(__fmul_rn(__fadd_rn((float)jz, 0.5f), bdk), k2);
        float dx = __fsub_rn(cqx, ckx);
        float dy = __fsub_rn(cqy, cky);
        float dz = __fsub_rn(cqz, ckz);
        float d2 = __fadd_rn(__fadd_rn(__fmul_rn(dx, dx), __fmul_rn(dy, dy)),
                             __fmul_rn(dz, dz));
        bool pos = false;
        if (d2 < thr2) {
            float dist = __fdiv_rn(__fsqrt_rn(d2), maxd);
            pos = dist < 0.5f;
        }
        unsigned long long m = __ballot(pos);
        if (pos) {
            int pref = __popcll(m & ((1ull << lane) - 1ull));
            int j = count + pref;
            if (j < MAXL)
                lists[((size_t)(n * MAXL + j)) * PP + p] = (unsigned short)pp;
        }
        count += (int)__popcll(m);
    }
    if (lane == 0)
        counts[n * PP + p] = count;
}

// Kernel B: block = (n, q-z-slab, 8-channel group). Stage the 2 feasible
// k z-slabs (8ch x 512 = 16KB) into LDS SoA rows; each thread owns one p,
// gathers from LDS (adjacent lanes -> near-adjacent idx, conflict-free),
// dots with coalesced q loads, block-reduces to partial[] (no atomics).
#define CC 8
__global__ __launch_bounds__(256) void dot_kernel(
    const float* __restrict__ q, const float* __restrict__ k,
    const float* __restrict__ coord_q, const float* __restrict__ coord_k,
    const int* __restrict__ counts, const unsigned short* __restrict__ lists,
    float* __restrict__ partial)
{
    __shared__ float klds[CC][512];
    __shared__ float red[256];

    int t  = threadIdx.x;
    int cg = blockIdx.x;          // 32 channel groups
    int zq = blockIdx.y;          // 8 q z-slabs
    int n  = blockIdx.z;
    int flat = (n * 8 + zq) * 32 + cg;
    int c0 = cg * CC;

    // Per-block scalar coord math (identical fp32 ops to mask_kernel).
    const float* cq = coord_q + n * 6;
    const float* ck = coord_k + n * 6;
    float q2 = cq[2], k2 = ck[2];
    float bwq = __fdiv_rn(__fsub_rn(cq[3], cq[0]), (float)WW);
    float bhq = __fdiv_rn(__fsub_rn(cq[4], cq[1]), (float)HH);
    float bdq = __fdiv_rn(__fsub_rn(cq[5], q2), (float)DD);
    float bwk = __fdiv_rn(__fsub_rn(ck[3], ck[0]), (float)WW);
    float bhk = __fdiv_rn(__fsub_rn(ck[4], ck[1]), (float)HH);
    float bdk = __fdiv_rn(__fsub_rn(ck[5], k2), (float)DD);
    float diagq = __fsqrt_rn(__fadd_rn(__fadd_rn(__fmul_rn(bwq, bwq), __fmul_rn(bhq, bhq)),
                                       __fmul_rn(bdq, bdq)));
    float diagk = __fsqrt_rn(__fadd_rn(__fadd_rn(__fmul_rn(bwk, bwk), __fmul_rn(bhk, bhk)),
                                       __fmul_rn(bdk, bdk)));
    float maxd = fmaxf(diagq, diagk);
    float cqz = __fadd_rn(__fmul_rn(__fadd_rn((float)zq, 0.5f), bdq), q2);

    int zk0 = z_window(cqz, bdk, k2, maxd);
    if (zk0 < 0) {                 // no feasible k-slab: numerator contribution 0
        if (t == 0) partial[flat] = 0.0f;
        return;
    }
    int base_p = zk0 << 8;

    // Stage k[n, c0..c0+7, base_p..base_p+511] -> LDS (float4, coalesced).
    {
        const float* ksrc = k + ((size_t)(n * CH + c0)) * PP + base_p;
        #pragma unroll
        for (int i = 0; i < 4; ++i) {
            int f = i * 256 + t;            // 1024 float4s total
            int c = f >> 7;                  // 128 float4 per 512-row
            int u = (f & 127) << 2;
            float4 v = *(const float4*)(ksrc + (size_t)c * PP + u);
            klds[c][u + 0] = v.x;
            klds[c][u + 1] = v.y;
            klds[c][u + 2] = v.z;
            klds[c][u + 3] = v.w;
        }
    }
    __syncthreads();

    int p = (zq << 8) + t;
    int cnt = counts[n * PP + p];
    cnt = cnt < MAXL ? cnt : MAXL;

    float s[CC];
    #pragma unroll
    for (int c = 0; c < CC; ++c) s[c] = 0.0f;

    const unsigned short* lp = lists + (size_t)n * MAXL * PP + p;
    int idx = (cnt > 0) ? ((int)lp[0] - base_p) : 0;
    for (int j = 0; j < cnt; ++j) {
        int nidx = (j + 1 < cnt) ? ((int)lp[(size_t)(j + 1) * PP] - base_p) : 0;
        #pragma unroll
        for (int c = 0; c < CC; ++c)
            s[c] += klds[c][idx];
        idx = nidx;
    }

    float acc = 0.0f;
    const float* qcol = q + ((size_t)(n * CH + c0)) * PP + p;
    #pragma unroll
    for (int c = 0; c < CC; ++c)
        acc += qcol[(size_t)c * PP] * s[c];

    red[t] = acc;
    __syncthreads();
    for (int off = 128; off > 0; off >>= 1) {
        if (t < off) red[t] += red[t + off];
        __syncthreads();
    }
    if (t == 0) partial[flat] = red[0];
}

// Final: one wave per batch sums partials (numerator) + true counts
// (denominator); thread 0 combines.
__global__ __launch_bounds__(512) void final_kernel(const float* __restrict__ partial,
                                                    const int* __restrict__ counts,
                                                    float* __restrict__ out)
{
    __shared__ float numsh[NB];
    __shared__ float densh[NB];
    int t = threadIdx.x;
    int n = t >> 6, lane = t & 63;

    float sp = 0.0f;
    for (int i = 0; i < 256 / 64; ++i)
        sp += partial[n * 256 + i * 64 + lane];
    int sc = 0;
    for (int i = 0; i < PP / 64; ++i)
        sc += counts[n * PP + i * 64 + lane];
    for (int off = 32; off > 0; off >>= 1) {
        sp += __shfl_down(sp, off, 64);
        sc += __shfl_down(sc, off, 64);
    }
    if (lane == 0) { numsh[n] = sp; densh[n] = (float)sc; }
    __syncthreads();
    if (t == 0) {
        float r = 0.0f;
        for (int i = 0; i < NB; ++i)
            r += numsh[i] / (densh[i] + 1e-6f);
        out[0] = -2.0f * (r / (float)NB);
    }
}

extern "C" void kernel_launch(void* const* d_in, const int* in_sizes, int n_in,
                              void* d_out, int out_size, void* d_ws, size_t ws_size,
                              hipStream_t stream) {
    const float* q       = (const float*)d_in[0];
    const float* k       = (const float*)d_in[1];
    const float* coord_q = (const float*)d_in[2];
    const float* coord_k = (const float*)d_in[3];
    float* out = (float*)d_out;

    char* w = (char*)d_ws;
    int* counts           = (int*)w;
    unsigned short* lists = (unsigned short*)(w + OFF_LIST);
    float* partial        = (float*)(w + OFF_PART);

    mask_kernel<<<(NB * PP) / 4, 256, 0, stream>>>(coord_q, coord_k, counts, lists);
    dot_kernel<<<dim3(CH / CC, DD, NB), 256, 0, stream>>>(q, k, coord_q, coord_k,
                                                          counts, lists, partial);
    final_kernel<<<1, 512, 0, stream>>>(partial, counts, out);
}

// Round 4
// 82.571 us; speedup vs baseline: 3.7864x; 1.0680x over previous
//
#include <hip/hip_runtime.h>
#include <cstdint>
#include <cstddef>

// Problem constants (from reference setup_inputs)
#define NB 8
#define CH 256
#define DD 8
#define HH 16
#define WW 16
#define PP 2048          // D*H*W ; one z-slab = HH*WW = 256 voxels

// Workspace layout (bytes):
//   [0,    8192)   float partial[NB*8*32]  (per-block numerator partials)
//   [8192, 8448)   float dpart[NB*8]       (per-(n,zq) denominator partials)
#define OFF_DPART 8192

// Geometric z-window (verified absmax 0.0 in R2/R3): any positive pair
// satisfies |czq - czk| < 0.5*maxd (fp32 monotonicity: d2 >= dz^2, sqrt/div
// RN monotone). Window spans at most 2 k z-slabs. Returns first feasible zk
// clamped to [0, DD-2], or -1 if none.
__device__ __forceinline__ int z_window(float czq, float bdk, float k2, float maxd) {
    float lim = 0.500060f * maxd;
    int zk0 = -1;
    #pragma unroll
    for (int zk = 0; zk < DD; ++zk) {
        float czk = __fadd_rn(__fmul_rn(__fadd_rn((float)zk, 0.5f), bdk), k2);
        bool feas = fabsf(__fsub_rn(czq, czk)) < lim;
        if (feas && zk0 < 0) zk0 = zk;
    }
    if (zk0 > DD - 2) zk0 = DD - 2;
    return zk0;
}

// Fused kernel: block = (cg, zq, n). Stages the 2 feasible k z-slabs
// (8 ch x 512 p' = 16KB) into LDS; each thread owns one q-voxel p,
// ENUMERATES its <=18 candidate k-voxels via per-dim index windows
// (x,y: <=3 bins each since radius/bin = 1.23; z: the 2 staged slabs),
// runs the exact fp32-mirrored positivity test per candidate, accumulates
// s[c] from LDS, dots with coalesced q loads, block-reduces numerator
// (all blocks) and true positive count (cg==0 blocks) to partials.
// No mask kernel, no lists/counts round-trip, no MAXL clamp.
#define CC 8
__global__ __launch_bounds__(256) void fused_kernel(
    const float* __restrict__ q, const float* __restrict__ k,
    const float* __restrict__ coord_q, const float* __restrict__ coord_k,
    float* __restrict__ partial, float* __restrict__ dpart)
{
    __shared__ float klds[CC][512];
    __shared__ float redf[256];
    __shared__ int   redi[256];

    int t  = threadIdx.x;
    int cg = blockIdx.x;          // 32 channel groups
    int zq = blockIdx.y;          // 8 q z-slabs
    int n  = blockIdx.z;
    int flat = (n * 8 + zq) * 32 + cg;
    int c0 = cg * CC;

    // Block-uniform coord math (identical fp32 ops to the verified R3 code).
    const float* cq = coord_q + n * 6;
    const float* ck = coord_k + n * 6;
    float q0 = cq[0], q1 = cq[1], q2 = cq[2];
    float k0 = ck[0], k1 = ck[1], k2 = ck[2];
    float bwq = __fdiv_rn(__fsub_rn(cq[3], q0), (float)WW);
    float bhq = __fdiv_rn(__fsub_rn(cq[4], q1), (float)HH);
    float bdq = __fdiv_rn(__fsub_rn(cq[5], q2), (float)DD);
    float bwk = __fdiv_rn(__fsub_rn(ck[3], k0), (float)WW);
    float bhk = __fdiv_rn(__fsub_rn(ck[4], k1), (float)HH);
    float bdk = __fdiv_rn(__fsub_rn(ck[5], k2), (float)DD);
    float diagq = __fsqrt_rn(__fadd_rn(__fadd_rn(__fmul_rn(bwq, bwq), __fmul_rn(bhq, bhq)),
                                       __fmul_rn(bdq, bdq)));
    float diagk = __fsqrt_rn(__fadd_rn(__fadd_rn(__fmul_rn(bwk, bwk), __fmul_rn(bhk, bhk)),
                                       __fmul_rn(bdk, bdk)));
    float maxd = fmaxf(diagq, diagk);
    float cqz = __fadd_rn(__fmul_rn(__fadd_rn((float)zq, 0.5f), bdq), q2);

    int zk0 = z_window(cqz, bdk, k2, maxd);
    if (zk0 < 0) {                 // no feasible k-slab for this q z-slab
        if (t == 0) {
            partial[flat] = 0.0f;
            if (cg == 0) dpart[n * 8 + zq] = 0.0f;
        }
        return;
    }
    int base_p = zk0 << 8;

    // Stage k[n, c0..c0+7, base_p..base_p+511] -> LDS (float4, coalesced).
    {
        const float* ksrc = k + ((size_t)(n * CH + c0)) * PP + base_p;
        #pragma unroll
        for (int i = 0; i < 4; ++i) {
            int f = i * 256 + t;            // 1024 float4s total
            int c = f >> 7;                  // 128 float4 per 512-row
            int u = (f & 127) << 2;
            float4 v = *(const float4*)(ksrc + (size_t)c * PP + u);
            klds[c][u + 0] = v.x;
            klds[c][u + 1] = v.y;
            klds[c][u + 2] = v.z;
            klds[c][u + 3] = v.w;
        }
    }
    __syncthreads();

    // This thread's q-voxel center (exact fp32 chain).
    int ix = t & 15, iy = (t >> 4) & 15;
    float cqx = __fadd_rn(__fmul_rn(__fadd_rn((float)ix, 0.5f), bwq), q0);
    float cqy = __fadd_rn(__fmul_rn(__fadd_rn((float)iy, 0.5f), bhq), q1);

    // Conservative per-dim index windows. A candidate outside the window has
    // |delta| >= lim in that dim, which (by fp monotonicity) forces
    // dist >= 0.5. Margins: lim carries +6e-5 rel; index radius +0.03 bins
    // (fp error in tx/rx is ~1e-6 rel). Enumerated candidates get the EXACT
    // test, so over-inclusion is harmless.
    float lim = 0.500060f * maxd;
    float tx = (cqx - k0) / bwk - 0.5f;
    float ty = (cqy - k1) / bhk - 0.5f;
    float rx = lim / bwk + 0.03f;
    float ry = lim / bhk + 0.03f;
    int jx0 = (int)ceilf(tx - rx);  if (jx0 < 0) jx0 = 0;
    int jx1 = (int)floorf(tx + rx); if (jx1 > WW - 1) jx1 = WW - 1;
    int jy0 = (int)ceilf(ty - ry);  if (jy0 < 0) jy0 = 0;
    int jy1 = (int)floorf(ty + ry); if (jy1 > HH - 1) jy1 = HH - 1;

    float half_maxd = 0.5f * maxd;
    float thr2 = half_maxd * half_maxd * 1.001f;   // prefilter; exact check inside

    float s[CC];
    #pragma unroll
    for (int c = 0; c < CC; ++c) s[c] = 0.0f;
    int cnt = 0;

    for (int dzI = 0; dzI < 2; ++dzI) {
        int jz = zk0 + dzI;
        float ckz = __fadd_rn(__fmul_rn(__fadd_rn((float)jz, 0.5f), bdk), k2);
        float dz  = __fsub_rn(cqz, ckz);
        float dz2 = __fmul_rn(dz, dz);
        for (int jy = jy0; jy <= jy1; ++jy) {
            float cky = __fadd_rn(__fmul_rn(__fadd_rn((float)jy, 0.5f), bhk), k1);
            float dy  = __fsub_rn(cqy, cky);
            float dy2 = __fmul_rn(dy, dy);
            for (int jx = jx0; jx <= jx1; ++jx) {
                float ckx = __fadd_rn(__fmul_rn(__fadd_rn((float)jx, 0.5f), bwk), k0);
                float dx  = __fsub_rn(cqx, ckx);
                float dx2 = __fmul_rn(dx, dx);
                float d2  = __fadd_rn(__fadd_rn(dx2, dy2), dz2);
                bool pos = false;
                if (d2 < thr2) {
                    float dist = __fdiv_rn(__fsqrt_rn(d2), maxd);
                    pos = dist < 0.5f;
                }
                if (pos) {
                    ++cnt;
                    int idx = (dzI << 8) + (jy << 4) + jx;
                    #pragma unroll
                    for (int c = 0; c < CC; ++c)
                        s[c] += klds[c][idx];
                }
            }
        }
    }

    // Dot with coalesced q loads.
    int p = (zq << 8) + t;
    float acc = 0.0f;
    const float* qcol = q + ((size_t)(n * CH + c0)) * PP + p;
    #pragma unroll
    for (int c = 0; c < CC; ++c)
        acc += qcol[(size_t)c * PP] * s[c];

    redf[t] = acc;
    redi[t] = cnt;
    __syncthreads();
    for (int off = 128; off > 0; off >>= 1) {
        if (t < off) { redf[t] += redf[t + off]; redi[t] += redi[t + off]; }
        __syncthreads();
    }
    if (t == 0) {
        partial[flat] = redf[0];
        if (cg == 0) dpart[n * 8 + zq] = (float)redi[0];
    }
}

// Final: one wave per batch sums 256 numerator partials + 8 denominator
// partials; thread 0 combines.
__global__ __launch_bounds__(512) void final_kernel(const float* __restrict__ partial,
                                                    const float* __restrict__ dpart,
                                                    float* __restrict__ out)
{
    __shared__ float numsh[NB];
    __shared__ float densh[NB];
    int t = threadIdx.x;
    int n = t >> 6, lane = t & 63;

    float sp = 0.0f;
    #pragma unroll
    for (int i = 0; i < 4; ++i)
        sp += partial[n * 256 + i * 64 + lane];
    float sc = (lane < 8) ? dpart[n * 8 + lane] : 0.0f;
    for (int off = 32; off > 0; off >>= 1) {
        sp += __shfl_down(sp, off, 64);
        sc += __shfl_down(sc, off, 64);
    }
    if (lane == 0) { numsh[n] = sp; densh[n] = sc; }
    __syncthreads();
    if (t == 0) {
        float r = 0.0f;
        for (int i = 0; i < NB; ++i)
            r += numsh[i] / (densh[i] + 1e-6f);
        out[0] = -2.0f * (r / (float)NB);
    }
}

extern "C" void kernel_launch(void* const* d_in, const int* in_sizes, int n_in,
                              void* d_out, int out_size, void* d_ws, size_t ws_size,
                              hipStream_t stream) {
    const float* q       = (const float*)d_in[0];
    const float* k       = (const float*)d_in[1];
    const float* coord_q = (const float*)d_in[2];
    const float* coord_k = (const float*)d_in[3];
    float* out = (float*)d_out;

    char* w = (char*)d_ws;
    float* partial = (float*)w;
    float* dpart   = (float*)(w + OFF_DPART);

    fused_kernel<<<dim3(CH / CC, DD, NB), 256, 0, stream>>>(q, k, coord_q, coord_k,
                                                            partial, dpart);
    final_kernel<<<1, 512, 0, stream>>>(partial, dpart, out);
}

// Round 5
// 80.388 us; speedup vs baseline: 3.8892x; 1.0272x over previous
//
#include <hip/hip_runtime.h>
#include <cstdint>
#include <cstddef>

// Problem constants (from reference setup_inputs)
#define NB 8
#define CH 256
#define DD 8
#define HH 16
#define WW 16
#define PP 2048          // D*H*W ; one z-slab = HH*WW = 256 voxels

// Workspace layout (bytes):
//   [0,     16384)   float partial[NB*8*16*4]  (per-wave numerator partials)
//   [16384, 17408)   float dpart[NB*8*4]       (per-wave denominator partials, cg==0)
#define OFF_DPART 16384

// Geometric z-window (verified absmax 0.0 in R2-R4): any positive pair
// satisfies |czq - czk| < 0.5*maxd (fp32 monotonicity: d2 >= dz^2, sqrt/div
// RN monotone). Window spans at most 2 k z-slabs. Returns first feasible zk
// clamped to [0, DD-2], or -1 if none.
__device__ __forceinline__ int z_window(float czq, float bdk, float k2, float maxd) {
    float lim = 0.500060f * maxd;
    int zk0 = -1;
    #pragma unroll
    for (int zk = 0; zk < DD; ++zk) {
        float czk = __fadd_rn(__fmul_rn(__fadd_rn((float)zk, 0.5f), bdk), k2);
        bool feas = fabsf(__fsub_rn(czq, czk)) < lim;
        if (feas && zk0 < 0) zk0 = zk;
    }
    if (zk0 > DD - 2) zk0 = DD - 2;
    return zk0;
}

// Fused kernel: block = (cg, zq, n), 1024 blocks = 4/CU (full residency).
// Stages the 2 feasible k z-slabs (16 ch x 512 p' = 32KB) into LDS; each
// thread owns one q-voxel p, enumerates its <=18 candidate k-voxels via
// per-dim index windows (x,y: <=3 bins; z: 2 staged slabs), runs the exact
// fp32-mirrored positivity test per candidate, accumulates s[c] from LDS,
// dots with prefetched q registers, wave-shuffle-reduces (no syncthreads)
// to one global write per wave.
#define CC 16
__global__ __launch_bounds__(256) void fused_kernel(
    const float* __restrict__ q, const float* __restrict__ k,
    const float* __restrict__ coord_q, const float* __restrict__ coord_k,
    float* __restrict__ partial, float* __restrict__ dpart)
{
    __shared__ float klds[CC][512];

    int t  = threadIdx.x;
    int wv = t >> 6;
    int lane = t & 63;
    int cg = blockIdx.x;          // 16 channel groups
    int zq = blockIdx.y;          // 8 q z-slabs
    int n  = blockIdx.z;
    int flat = (n * 8 + zq) * 16 + cg;
    int c0 = cg * CC;

    // Block-uniform coord math (identical fp32 ops to the verified R4 code).
    const float* cq = coord_q + n * 6;
    const float* ck = coord_k + n * 6;
    float q0 = cq[0], q1 = cq[1], q2 = cq[2];
    float k0 = ck[0], k1 = ck[1], k2 = ck[2];
    float bwq = __fdiv_rn(__fsub_rn(cq[3], q0), (float)WW);
    float bhq = __fdiv_rn(__fsub_rn(cq[4], q1), (float)HH);
    float bdq = __fdiv_rn(__fsub_rn(cq[5], q2), (float)DD);
    float bwk = __fdiv_rn(__fsub_rn(ck[3], k0), (float)WW);
    float bhk = __fdiv_rn(__fsub_rn(ck[4], k1), (float)HH);
    float bdk = __fdiv_rn(__fsub_rn(ck[5], k2), (float)DD);
    float diagq = __fsqrt_rn(__fadd_rn(__fadd_rn(__fmul_rn(bwq, bwq), __fmul_rn(bhq, bhq)),
                                       __fmul_rn(bdq, bdq)));
    float diagk = __fsqrt_rn(__fadd_rn(__fadd_rn(__fmul_rn(bwk, bwk), __fmul_rn(bhk, bhk)),
                                       __fmul_rn(bdk, bdk)));
    float maxd = fmaxf(diagq, diagk);
    float cqz = __fadd_rn(__fmul_rn(__fadd_rn((float)zq, 0.5f), bdq), q2);

    int zk0 = z_window(cqz, bdk, k2, maxd);
    if (zk0 < 0) {                 // no feasible k-slab for this q z-slab
        if (lane == 0) {
            partial[flat * 4 + wv] = 0.0f;
            if (cg == 0) dpart[(n * 8 + zq) * 4 + wv] = 0.0f;
        }
        return;
    }
    int base_p = zk0 << 8;

    // Prefetch this thread's q values (coalesced per c; latency hides under
    // LDS staging + gather).
    int p = (zq << 8) + t;
    float qv[CC];
    {
        const float* qcol = q + ((size_t)(n * CH + c0)) * PP + p;
        #pragma unroll
        for (int c = 0; c < CC; ++c)
            qv[c] = qcol[(size_t)c * PP];
    }

    // Stage k[n, c0..c0+15, base_p..base_p+511] -> LDS (float4, coalesced).
    {
        const float* ksrc = k + ((size_t)(n * CH + c0)) * PP + base_p;
        #pragma unroll
        for (int i = 0; i < 8; ++i) {
            int f = i * 256 + t;            // 2048 float4s total
            int c = f >> 7;                  // 128 float4 per 512-row
            int u = (f & 127) << 2;
            float4 v = *(const float4*)(ksrc + (size_t)c * PP + u);
            klds[c][u + 0] = v.x;
            klds[c][u + 1] = v.y;
            klds[c][u + 2] = v.z;
            klds[c][u + 3] = v.w;
        }
    }
    __syncthreads();

    // This thread's q-voxel center (exact fp32 chain).
    int ix = t & 15, iy = (t >> 4) & 15;
    float cqx = __fadd_rn(__fmul_rn(__fadd_rn((float)ix, 0.5f), bwq), q0);
    float cqy = __fadd_rn(__fmul_rn(__fadd_rn((float)iy, 0.5f), bhq), q1);

    // Conservative per-dim index windows; enumerated candidates get the
    // EXACT test, so over-inclusion is harmless (verified absmax 0.0).
    float lim = 0.500060f * maxd;
    float tx = (cqx - k0) / bwk - 0.5f;
    float ty = (cqy - k1) / bhk - 0.5f;
    float rx = lim / bwk + 0.03f;
    float ry = lim / bhk + 0.03f;
    int jx0 = (int)ceilf(tx - rx);  if (jx0 < 0) jx0 = 0;
    int jx1 = (int)floorf(tx + rx); if (jx1 > WW - 1) jx1 = WW - 1;
    int jy0 = (int)ceilf(ty - ry);  if (jy0 < 0) jy0 = 0;
    int jy1 = (int)floorf(ty + ry); if (jy1 > HH - 1) jy1 = HH - 1;

    float half_maxd = 0.5f * maxd;
    float thr2 = half_maxd * half_maxd * 1.001f;   // prefilter; exact check inside

    float s[CC];
    #pragma unroll
    for (int c = 0; c < CC; ++c) s[c] = 0.0f;
    int cnt = 0;

    for (int dzI = 0; dzI < 2; ++dzI) {
        int jz = zk0 + dzI;
        float ckz = __fadd_rn(__fmul_rn(__fadd_rn((float)jz, 0.5f), bdk), k2);
        float dz  = __fsub_rn(cqz, ckz);
        float dz2 = __fmul_rn(dz, dz);
        for (int jy = jy0; jy <= jy1; ++jy) {
            float cky = __fadd_rn(__fmul_rn(__fadd_rn((float)jy, 0.5f), bhk), k1);
            float dy  = __fsub_rn(cqy, cky);
            float dy2 = __fmul_rn(dy, dy);
            for (int jx = jx0; jx <= jx1; ++jx) {
                float ckx = __fadd_rn(__fmul_rn(__fadd_rn((float)jx, 0.5f), bwk), k0);
                float dx  = __fsub_rn(cqx, ckx);
                float dx2 = __fmul_rn(dx, dx);
                float d2  = __fadd_rn(__fadd_rn(dx2, dy2), dz2);
                bool pos = false;
                if (d2 < thr2) {
                    float dist = __fdiv_rn(__fsqrt_rn(d2), maxd);
                    pos = dist < 0.5f;
                }
                if (pos) {
                    ++cnt;
                    int idx = (dzI << 8) + (jy << 4) + jx;
                    #pragma unroll
                    for (int c = 0; c < CC; ++c)
                        s[c] += klds[c][idx];
                }
            }
        }
    }

    float acc = 0.0f;
    #pragma unroll
    for (int c = 0; c < CC; ++c)
        acc += qv[c] * s[c];

    // Wave-shuffle reduction (no syncthreads), one write per wave.
    int ci = cnt;
    #pragma unroll
    for (int off = 32; off > 0; off >>= 1) {
        acc += __shfl_down(acc, off, 64);
        ci  += __shfl_down(ci, off, 64);
    }
    if (lane == 0) {
        partial[flat * 4 + wv] = acc;
        if (cg == 0) dpart[(n * 8 + zq) * 4 + wv] = (float)ci;
    }
}

// Final: one wave per batch sums 512 numerator partials + 32 denominator
// partials; thread 0 combines.
__global__ __launch_bounds__(512) void final_kernel(const float* __restrict__ partial,
                                                    const float* __restrict__ dpart,
                                                    float* __restrict__ out)
{
    __shared__ float numsh[NB];
    __shared__ float densh[NB];
    int t = threadIdx.x;
    int n = t >> 6, lane = t & 63;

    float sp = 0.0f;
    #pragma unroll
    for (int i = 0; i < 8; ++i)
        sp += partial[n * 512 + i * 64 + lane];
    float sc = (lane < 32) ? dpart[n * 32 + lane] : 0.0f;
    #pragma unroll
    for (int off = 32; off > 0; off >>= 1) {
        sp += __shfl_down(sp, off, 64);
        sc += __shfl_down(sc, off, 64);
    }
    if (lane == 0) { numsh[n] = sp; densh[n] = sc; }
    __syncthreads();
    if (t == 0) {
        float r = 0.0f;
        for (int i = 0; i < NB; ++i)
            r += numsh[i] / (densh[i] + 1e-6f);
        out[0] = -2.0f * (r / (float)NB);
    }
}

extern "C" void kernel_launch(void* const* d_in, const int* in_sizes, int n_in,
                              void* d_out, int out_size, void* d_ws, size_t ws_size,
                              hipStream_t stream) {
    const float* q       = (const float*)d_in[0];
    const float* k       = (const float*)d_in[1];
    const float* coord_q = (const float*)d_in[2];
    const float* coord_k = (const float*)d_in[3];
    float* out = (float*)d_out;

    char* w = (char*)d_ws;
    float* partial = (float*)w;
    float* dpart   = (float*)(w + OFF_DPART);

    fused_kernel<<<dim3(CH / CC, DD, NB), 256, 0, stream>>>(q, k, coord_q, coord_k,
                                                            partial, dpart);
    final_kernel<<<1, 512, 0, stream>>>(partial, dpart, out);
}